// Round 22
// baseline (328.254 us; speedup 1.0000x reference)
//
#include <hip/hip_runtime.h>

typedef __attribute__((ext_vector_type(8))) short short8;
typedef __attribute__((ext_vector_type(4))) float f32x4;
typedef __attribute__((ext_vector_type(16))) float f32x16;

#define MFMA16(A,B,C) __builtin_amdgcn_mfma_f32_16x16x32_bf16(A,B,C,0,0,0)
#define MFMA32(A,B,C) __builtin_amdgcn_mfma_f32_32x32x16_bf16(A,B,C,0,0,0)

__device__ __forceinline__ short f2bf(float f){
  union { float f; unsigned int u; } v; v.f = f;
  unsigned int u = v.u;
  unsigned int r = (u + 0x7fffu + ((u >> 16) & 1u)) >> 16;
  return (short)r;
}

// Round-half-up two floats to bf16 and pack (low = x, high = y):
// 2 x v_add_u32 + 1 x v_perm_b32, all compiler-generated.
__device__ __forceinline__ unsigned pk2bf_hu(float x, float y){
  unsigned a = __builtin_bit_cast(unsigned, x) + 0x8000u;
  unsigned b = __builtin_bit_cast(unsigned, y) + 0x8000u;
  return __builtin_amdgcn_perm(b, a, 0x07060302u);  // {b.hi16, a.hi16}
}

typedef const __attribute__((address_space(1))) void* gptr_t;
typedef __attribute__((address_space(3))) void* lptr_t;

__device__ __forceinline__ void gload16(const short* g, short* l){
  __builtin_amdgcn_global_load_lds((gptr_t)g, (lptr_t)l, 16, 0, 0);
}

// ---------------- converts ----------------

__global__ __launch_bounds__(256) void cvt_x_kernel(const float* __restrict__ x,
                                                    short* __restrict__ xb){
  const size_t i = (size_t)blockIdx.x * 256 + threadIdx.x;
  const float4* p = (const float4*)x + i * 2;
  float4 a = p[0], b = p[1];
  short8 o;
  o[0]=f2bf(a.x); o[1]=f2bf(a.y); o[2]=f2bf(a.z); o[3]=f2bf(a.w);
  o[4]=f2bf(b.x); o[5]=f2bf(b.y); o[6]=f2bf(b.z); o[7]=f2bf(b.w);
  *(short8*)(xb + i * 8) = o;
}

// src[R][C] f32 -> dst[C][R] bf16
__global__ __launch_bounds__(256) void cvt_t_kernel(const float* __restrict__ src,
                                                    short* __restrict__ dst,
                                                    int R, int C){
  __shared__ float tile[32][33];
  const int tx = threadIdx.x, ty = threadIdx.y;
  const int c0 = blockIdx.x * 32, r0 = blockIdx.y * 32;
  #pragma unroll
  for (int i = 0; i < 32; i += 8)
    tile[ty + i][tx] = src[(size_t)(r0 + ty + i) * C + c0 + tx];
  __syncthreads();
  #pragma unroll
  for (int i = 0; i < 32; i += 8)
    dst[(size_t)(c0 + ty + i) * R + r0 + tx] = f2bf(tile[tx][ty + i]);
}

// ---------------- GEMM: C[M][N] = A[M][1024] * BT[N][1024]^T + bias ----------------
// Frozen at r21 (verified best): r18 K-loop, bn = blockIdx.x fast (A-panel
// consumers co-resident), __launch_bounds__(256,4).
// EPI 0: QKV epilogue (Q pre-scaled by 0.125*log2e). V^T stored RE-TILED:
// [head][32 Ltile][64 d][64 Lw].

template<int EPI>
__global__ __launch_bounds__(256, 4) void gemm_bt(
    const short* __restrict__ A, const short* __restrict__ BT,
    const float* __restrict__ bias,
    float* __restrict__ Cf,
    short* __restrict__ q_ws, short* __restrict__ k_ws, short* __restrict__ vt_ws)
{
  __shared__ __align__(16) short As[4096];  // [128][32]
  __shared__ __align__(16) short Bs[4096];  // [128][32]
  const int tid = threadIdx.x;
  const int bn = blockIdx.x, bm = blockIdx.y;   // bn fast (axis swap)
  const int lane = tid & 63, wid = tid >> 6;
  const int wr = wid >> 1, wc = wid & 1;
  const int r = lane & 15, g = lane >> 4;

  f32x4 acc[4][4] = {};

  const short* ag = A  + (size_t)(bm * 128 + (tid >> 2)) * 1024 + (tid & 3) * 8;
  const short* bg = BT + (size_t)(bn * 128 + (tid >> 2)) * 1024 + (tid & 3) * 8;
  short* asd = &As[tid * 8];
  short* bsd = &Bs[tid * 8];

  for (int kk = 0; kk < 32; ++kk){
    gload16(ag + kk * 32,             asd);
    gload16(ag + kk * 32 + 64 * 1024, asd + 2048);
    gload16(bg + kk * 32,             bsd);
    gload16(bg + kk * 32 + 64 * 1024, bsd + 2048);
    asm volatile("s_waitcnt vmcnt(0)" ::: "memory");
    __syncthreads();
    short8 a[4], b[4];
    #pragma unroll
    for (int mf = 0; mf < 4; ++mf)
      a[mf] = *(const short8*)&As[(wr * 64 + mf * 16 + r) * 32 + g * 8];
    #pragma unroll
    for (int nf = 0; nf < 4; ++nf)
      b[nf] = *(const short8*)&Bs[(wc * 64 + nf * 16 + r) * 32 + g * 8];
    #pragma unroll
    for (int mf = 0; mf < 4; ++mf)
      #pragma unroll
      for (int nf = 0; nf < 4; ++nf)
        acc[mf][nf] = MFMA16(a[mf], b[nf], acc[mf][nf]);
    __syncthreads();
  }

  if (EPI == 0){
    #pragma unroll
    for (int nf = 0; nf < 4; ++nf){
      const int c = bn * 128 + wc * 64 + nf * 16 + r;
      const float bv = bias[c];
      const int type = c >> 10;
      const int h = (c & 1023) >> 6, d = c & 63;
      const float mul = (type == 0) ? 0.18033688011112042f : 1.0f;  // sc*log2e
      #pragma unroll
      for (int mf = 0; mf < 4; ++mf){
        const int row0 = bm * 128 + wr * 64 + mf * 16 + g * 4;
        const int nb = row0 >> 11, l0 = row0 & 2047;
        f32x4 v = acc[mf][nf];
        if (type == 2){
          short4 pk;
          pk.x = f2bf(v[0] + bv); pk.y = f2bf(v[1] + bv);
          pk.z = f2bf(v[2] + bv); pk.w = f2bf(v[3] + bv);
          const int head = nb * 16 + h;
          *(short4*)&vt_ws[(((size_t)head * 32 + (l0 >> 6)) * 64 + d) * 64 + (l0 & 63)] = pk;
        } else {
          short* dst = (type == 0) ? q_ws : k_ws;
          const size_t base = ((size_t)(nb * 16 + h) * 2048 + l0) * 64 + d;
          #pragma unroll
          for (int j = 0; j < 4; ++j)
            dst[base + (size_t)j * 64] = f2bf((v[j] + bv) * mul);
        }
      }
    }
  } else {
    #pragma unroll
    for (int nf = 0; nf < 4; ++nf){
      const int c = bn * 128 + wc * 64 + nf * 16 + r;
      const float bv = bias[c];
      #pragma unroll
      for (int mf = 0; mf < 4; ++mf){
        const int row0 = bm * 128 + wr * 64 + mf * 16 + g * 4;
        f32x4 v = acc[mf][nf];
        #pragma unroll
        for (int j = 0; j < 4; ++j)
          Cf[(size_t)(row0 + j) * 1024 + c] = v[j] + bv;
      }
    }
  }
}

// ---------------- flash attention: phase-interleaved 2-tile rounds ----------
// Shell frozen (r16/r21-verified): sync round = 2 tiles, vmcnt(0) + fenced
// s_barrier per round, 4 buffers with literal indices. Core ops frozen at
// r17: raw v_exp_f32 + pk2bf_hu (compiler-visible), builtin permlane32_swap,
// ones-B MFMA row sums. NEVER feed v_exp_f32 into opaque inline asm.
// NEW this round: within-wave phase interleave. Round issue order becomes
// QK(a), QK(b), SM(a), PV(a), SM(b), PV(b) — SM(a)'s VALU hides under
// QK(b)'s MFMA pipe time, SM(b) under PV(a). (r21 counters: MfmaUtil 47.5 +
// VALUBusy 49.7 with barrier-aligned phases = serialized pipes, not bound.)

__global__ __launch_bounds__(512, 4) void attn_kernel(
    const short* __restrict__ qw, const short* __restrict__ kw,
    const short* __restrict__ vtw, short* __restrict__ ow)
{
  __shared__ __align__(16) short Ks[4][4096];   // [64][64] swizzled
  __shared__ __align__(16) short Vs[4][4096];   // [64 d][64 Lw] swizzled

  const int id = blockIdx.x;
  const int xcd = id & 7, j2 = id >> 3;
  const int nh = xcd * 8 + (j2 & 7);         // 8 heads per XCD, head-coherent
  const int qt = j2 >> 3;                    // q-tile 0..7 (256 rows each)
  const int tid = threadIdx.x;
  const int lane = tid & 63, w = tid >> 6;
  const int l31 = lane & 31, hi = lane >> 5, w7 = lane & 7;

  const size_t hoff = (size_t)nh * 2048 * 64;
  const short* kh = kw + hoff;
  const short* vh = vtw + hoff;

  const int srow = tid >> 3, schunk = tid & 7;
  const int scw = (schunk ^ (srow & 7)) * 8;
  const short* ksrc = kh + srow * 64 + scw;              // + t*4096
  const short* vsrc = vh + srow * 64 + scw;              // + t*4096 (re-tiled)

  unsigned aoffh[2][4];
  #pragma unroll
  for (int T = 0; T < 2; ++T)
    #pragma unroll
    for (int s = 0; s < 4; ++s)
      aoffh[T][s] = (unsigned)((l31 + 32 * T) * 64 + (((2 * s + hi) ^ w7) * 8));

  const int qrow0 = qt * 256 + w * 32;
  short8 qfr[4];
  #pragma unroll
  for (int s = 0; s < 4; ++s)
    qfr[s] = *(const short8*)(qw + hoff + (size_t)(qrow0 + l31) * 64 + s * 16 + hi * 8);

  f32x16 oa0 = {}, oa1 = {}, lacc = {};
  short8 onesB;
  #pragma unroll
  for (int i = 0; i < 8; ++i) onesB[i] = (short)0x3F80;  // bf16 1.0

  // phase pieces
  auto qk = [&](const short* Kb, f32x16& ss0, f32x16& ss1){
    const f32x16 zz = {};
    ss0 = MFMA32(*(const short8*)&Kb[aoffh[0][0]], qfr[0], zz);
    ss1 = MFMA32(*(const short8*)&Kb[aoffh[1][0]], qfr[0], zz);
    #pragma unroll
    for (int s = 1; s < 4; ++s){
      ss0 = MFMA32(*(const short8*)&Kb[aoffh[0][s]], qfr[s], ss0);
      ss1 = MFMA32(*(const short8*)&Kb[aoffh[1][s]], qfr[s], ss1);
    }
  };

  auto smpack = [&](const f32x16& ss0, const f32x16& ss1, short8* pa){
    unsigned u0[8], u1[8];
    #pragma unroll
    for (int m = 0; m < 8; ++m){
      u0[m] = pk2bf_hu(__builtin_amdgcn_exp2f(ss0[2 * m]),
                       __builtin_amdgcn_exp2f(ss0[2 * m + 1]));
      u1[m] = pk2bf_hu(__builtin_amdgcn_exp2f(ss1[2 * m]),
                       __builtin_amdgcn_exp2f(ss1[2 * m + 1]));
    }
    #pragma unroll
    for (int s = 0; s < 4; ++s){
      const int sg = (s & 1) * 4;
      unsigned a0 = (s < 2) ? u0[sg + 0] : u1[sg + 0];
      unsigned a1 = (s < 2) ? u0[sg + 1] : u1[sg + 1];
      unsigned a2 = (s < 2) ? u0[sg + 2] : u1[sg + 2];
      unsigned a3 = (s < 2) ? u0[sg + 3] : u1[sg + 3];
      auto r02 = __builtin_amdgcn_permlane32_swap(a0, a2, false, false);
      auto r13 = __builtin_amdgcn_permlane32_swap(a1, a3, false, false);
      union { unsigned q[4]; short8 s8; } cv;
      cv.q[0] = (unsigned)r02[0]; cv.q[1] = (unsigned)r13[0];
      cv.q[2] = (unsigned)r02[1]; cv.q[3] = (unsigned)r13[1];
      pa[s] = cv.s8;
    }
  };

  auto pv = [&](const short8* pa, const short* Vb){
    #pragma unroll
    for (int s = 0; s < 4; ++s){
      oa0  = MFMA32(pa[s], *(const short8*)&Vb[aoffh[0][s]], oa0);
      oa1  = MFMA32(pa[s], *(const short8*)&Vb[aoffh[1][s]], oa1);
      lacc = MFMA32(pa[s], onesB, lacc);
    }
  };

  // interleaved pair: QK(a), QK(b), SM(a), PV(a), SM(b), PV(b)
  auto compute_pair = [&](const short* Ka, const short* Va,
                          const short* Kb, const short* Vb){
    f32x16 sa0, sa1, sb0, sb1;
    qk(Ka, sa0, sa1);
    qk(Kb, sb0, sb1);
    short8 paA[4], paB[4];
    smpack(sa0, sa1, paA);
    pv(paA, Va);
    smpack(sb0, sb1, paB);
    pv(paB, Vb);
  };

  // prologue: stage tiles 0,1 into buffers 0,1
  gload16(ksrc,        &Ks[0][tid * 8]);
  gload16(vsrc,        &Vs[0][tid * 8]);
  gload16(ksrc + 4096, &Ks[1][tid * 8]);
  gload16(vsrc + 4096, &Vs[1][tid * 8]);

  for (int p = 0; p < 8; ++p){
    const int t0 = p * 4;
    asm volatile("s_waitcnt vmcnt(0)" ::: "memory");
    asm volatile("s_barrier" ::: "memory");
    gload16(ksrc + (t0 + 2) * 4096, &Ks[2][tid * 8]);
    gload16(vsrc + (t0 + 2) * 4096, &Vs[2][tid * 8]);
    gload16(ksrc + (t0 + 3) * 4096, &Ks[3][tid * 8]);
    gload16(vsrc + (t0 + 3) * 4096, &Vs[3][tid * 8]);
    compute_pair(&Ks[0][0], &Vs[0][0], &Ks[1][0], &Vs[1][0]);
    asm volatile("s_waitcnt vmcnt(0)" ::: "memory");
    asm volatile("s_barrier" ::: "memory");
    {
      const int ts0 = (t0 + 4) & 31;   // p=7: dummy re-stage of tiles 0,1
      const int ts1 = (t0 + 5) & 31;
      gload16(ksrc + ts0 * 4096, &Ks[0][tid * 8]);
      gload16(vsrc + ts0 * 4096, &Vs[0][tid * 8]);
      gload16(ksrc + ts1 * 4096, &Ks[1][tid * 8]);
      gload16(vsrc + ts1 * 4096, &Vs[1][tid * 8]);
    }
    compute_pair(&Ks[2][0], &Vs[2][0], &Ks[3][0], &Vs[3][0]);
  }

  const int n = nh >> 4, h = nh & 15;
  #pragma unroll
  for (int j = 0; j < 16; ++j){
    const float inv = 1.0f / lacc[j];
    const int qr = (j & 3) + 8 * (j >> 2) + 4 * hi;
    const size_t base = ((size_t)n * 2048 + qrow0 + qr) * 1024 + h * 64 + l31;
    ow[base]      = f2bf(oa0[j] * inv);
    ow[base + 32] = f2bf(oa1[j] * inv);
  }
}

// ---------------- launch ----------------

extern "C" void kernel_launch(void* const* d_in, const int* in_sizes, int n_in,
                              void* d_out, int out_size, void* d_ws, size_t ws_size,
                              hipStream_t stream){
  const float* attn_in = (const float*)d_in[0];
  const float* W_qkv   = (const float*)d_in[1];
  const float* b_qkv   = (const float*)d_in[2];
  const float* W_out   = (const float*)d_in[3];
  const float* b_out   = (const float*)d_in[4];
  float* out = (float*)d_out;

  char* ws = (char*)d_ws;
  short* xb    = (short*)(ws);              // 16 MB  [8192][1024]
  short* wqT   = (short*)(ws + 16777216);   // 6 MB   [3072][1024]
  short* woT   = (short*)(ws + 23068672);   // 2 MB   [1024][1024]
  short* q_ws  = (short*)(ws + 25165824);   // 16 MB  [64][2048][64]
  short* k_ws  = (short*)(ws + 41943040);   // 16 MB
  short* vt_ws = (short*)(ws + 58720256);   // 16 MB  [64][32][64][64]
  short* o_ws  = (short*)(ws + 75497472);   // 16 MB  [8192][1024]

  cvt_x_kernel<<<4096, 256, 0, stream>>>(attn_in, xb);
  cvt_t_kernel<<<dim3(96, 32), dim3(32, 8), 0, stream>>>(W_qkv, wqT, 1024, 3072);
  cvt_t_kernel<<<dim3(32, 32), dim3(32, 8), 0, stream>>>(W_out, woT, 1024, 1024);
  gemm_bt<0><<<dim3(24, 64), 256, 0, stream>>>(xb, wqT, b_qkv, nullptr, q_ws, k_ws, vt_ws);
  attn_kernel<<<512, 512, 0, stream>>>(q_ws, k_ws, vt_ws, o_ws);
  gemm_bt<1><<<dim3(8, 64), 256, 0, stream>>>(o_ws, woT, b_out, out, nullptr, nullptr, nullptr);
}

// Round 23
// 187.320 us; speedup vs baseline: 1.7524x; 1.7524x over previous
//
#include <hip/hip_runtime.h>

typedef __attribute__((ext_vector_type(8))) short short8;
typedef __attribute__((ext_vector_type(4))) float f32x4;
typedef __attribute__((ext_vector_type(16))) float f32x16;

#define MFMA16(A,B,C) __builtin_amdgcn_mfma_f32_16x16x32_bf16(A,B,C,0,0,0)
#define MFMA32(A,B,C) __builtin_amdgcn_mfma_f32_32x32x16_bf16(A,B,C,0,0,0)

__device__ __forceinline__ short f2bf(float f){
  union { float f; unsigned int u; } v; v.f = f;
  unsigned int u = v.u;
  unsigned int r = (u + 0x7fffu + ((u >> 16) & 1u)) >> 16;
  return (short)r;
}

// Round-half-up two floats to bf16 and pack (low = x, high = y):
// 2 x v_add_u32 + 1 x v_perm_b32, all compiler-generated.
__device__ __forceinline__ unsigned pk2bf_hu(float x, float y){
  unsigned a = __builtin_bit_cast(unsigned, x) + 0x8000u;
  unsigned b = __builtin_bit_cast(unsigned, y) + 0x8000u;
  return __builtin_amdgcn_perm(b, a, 0x07060302u);  // {b.hi16, a.hi16}
}

typedef const __attribute__((address_space(1))) void* gptr_t;
typedef __attribute__((address_space(3))) void* lptr_t;

__device__ __forceinline__ void gload16(const short* g, short* l){
  __builtin_amdgcn_global_load_lds((gptr_t)g, (lptr_t)l, 16, 0, 0);
}

// ---------------- converts ----------------

__global__ __launch_bounds__(256) void cvt_x_kernel(const float* __restrict__ x,
                                                    short* __restrict__ xb){
  const size_t i = (size_t)blockIdx.x * 256 + threadIdx.x;
  const float4* p = (const float4*)x + i * 2;
  float4 a = p[0], b = p[1];
  short8 o;
  o[0]=f2bf(a.x); o[1]=f2bf(a.y); o[2]=f2bf(a.z); o[3]=f2bf(a.w);
  o[4]=f2bf(b.x); o[5]=f2bf(b.y); o[6]=f2bf(b.z); o[7]=f2bf(b.w);
  *(short8*)(xb + i * 8) = o;
}

// src[R][C] f32 -> dst[C][R] bf16
__global__ __launch_bounds__(256) void cvt_t_kernel(const float* __restrict__ src,
                                                    short* __restrict__ dst,
                                                    int R, int C){
  __shared__ float tile[32][33];
  const int tx = threadIdx.x, ty = threadIdx.y;
  const int c0 = blockIdx.x * 32, r0 = blockIdx.y * 32;
  #pragma unroll
  for (int i = 0; i < 32; i += 8)
    tile[ty + i][tx] = src[(size_t)(r0 + ty + i) * C + c0 + tx];
  __syncthreads();
  #pragma unroll
  for (int i = 0; i < 32; i += 8)
    dst[(size_t)(c0 + ty + i) * R + r0 + tx] = f2bf(tile[tx][ty + i]);
}

// ---------------- GEMM: C[M][N] = A[M][1024] * BT[N][1024]^T + bias ----------------
// Frozen at r21 (verified best): r18 K-loop, bn = blockIdx.x fast (A-panel
// consumers co-resident), __launch_bounds__(256,4).
// EPI 0: QKV epilogue (Q pre-scaled by 0.125*log2e). V^T stored RE-TILED:
// [head][32 Ltile][64 d][64 Lw].

template<int EPI>
__global__ __launch_bounds__(256, 4) void gemm_bt(
    const short* __restrict__ A, const short* __restrict__ BT,
    const float* __restrict__ bias,
    float* __restrict__ Cf,
    short* __restrict__ q_ws, short* __restrict__ k_ws, short* __restrict__ vt_ws)
{
  __shared__ __align__(16) short As[4096];  // [128][32]
  __shared__ __align__(16) short Bs[4096];  // [128][32]
  const int tid = threadIdx.x;
  const int bn = blockIdx.x, bm = blockIdx.y;   // bn fast (axis swap)
  const int lane = tid & 63, wid = tid >> 6;
  const int wr = wid >> 1, wc = wid & 1;
  const int r = lane & 15, g = lane >> 4;

  f32x4 acc[4][4] = {};

  const short* ag = A  + (size_t)(bm * 128 + (tid >> 2)) * 1024 + (tid & 3) * 8;
  const short* bg = BT + (size_t)(bn * 128 + (tid >> 2)) * 1024 + (tid & 3) * 8;
  short* asd = &As[tid * 8];
  short* bsd = &Bs[tid * 8];

  for (int kk = 0; kk < 32; ++kk){
    gload16(ag + kk * 32,             asd);
    gload16(ag + kk * 32 + 64 * 1024, asd + 2048);
    gload16(bg + kk * 32,             bsd);
    gload16(bg + kk * 32 + 64 * 1024, bsd + 2048);
    asm volatile("s_waitcnt vmcnt(0)" ::: "memory");
    __syncthreads();
    short8 a[4], b[4];
    #pragma unroll
    for (int mf = 0; mf < 4; ++mf)
      a[mf] = *(const short8*)&As[(wr * 64 + mf * 16 + r) * 32 + g * 8];
    #pragma unroll
    for (int nf = 0; nf < 4; ++nf)
      b[nf] = *(const short8*)&Bs[(wc * 64 + nf * 16 + r) * 32 + g * 8];
    #pragma unroll
    for (int mf = 0; mf < 4; ++mf)
      #pragma unroll
      for (int nf = 0; nf < 4; ++nf)
        acc[mf][nf] = MFMA16(a[mf], b[nf], acc[mf][nf]);
    __syncthreads();
  }

  if (EPI == 0){
    #pragma unroll
    for (int nf = 0; nf < 4; ++nf){
      const int c = bn * 128 + wc * 64 + nf * 16 + r;
      const float bv = bias[c];
      const int type = c >> 10;
      const int h = (c & 1023) >> 6, d = c & 63;
      const float mul = (type == 0) ? 0.18033688011112042f : 1.0f;  // sc*log2e
      #pragma unroll
      for (int mf = 0; mf < 4; ++mf){
        const int row0 = bm * 128 + wr * 64 + mf * 16 + g * 4;
        const int nb = row0 >> 11, l0 = row0 & 2047;
        f32x4 v = acc[mf][nf];
        if (type == 2){
          short4 pk;
          pk.x = f2bf(v[0] + bv); pk.y = f2bf(v[1] + bv);
          pk.z = f2bf(v[2] + bv); pk.w = f2bf(v[3] + bv);
          const int head = nb * 16 + h;
          *(short4*)&vt_ws[(((size_t)head * 32 + (l0 >> 6)) * 64 + d) * 64 + (l0 & 63)] = pk;
        } else {
          short* dst = (type == 0) ? q_ws : k_ws;
          const size_t base = ((size_t)(nb * 16 + h) * 2048 + l0) * 64 + d;
          #pragma unroll
          for (int j = 0; j < 4; ++j)
            dst[base + (size_t)j * 64] = f2bf((v[j] + bv) * mul);
        }
      }
    }
  } else {
    #pragma unroll
    for (int nf = 0; nf < 4; ++nf){
      const int c = bn * 128 + wc * 64 + nf * 16 + r;
      const float bv = bias[c];
      #pragma unroll
      for (int mf = 0; mf < 4; ++mf){
        const int row0 = bm * 128 + wr * 64 + mf * 16 + g * 4;
        f32x4 v = acc[mf][nf];
        #pragma unroll
        for (int j = 0; j < 4; ++j)
          Cf[(size_t)(row0 + j) * 1024 + c] = v[j] + bv;
      }
    }
  }
}

// ---------------- flash attention: 2-tiles-per-barrier LDS pipeline ---------
// Structure reverted to r21-exact (verified best; r22's explicit phase
// interleave spilled 4 live f32x16 S-tiles under the 128-VGPR cap ->
// 465MB scratch writes, 81->222us). Single delta vs r21: s_setprio(1)
// around the MFMA clusters (T5: measured +4-7% on attn with multi-wave
// phase diversity; pure scheduler hint, no correctness surface).
// Core ops frozen: raw v_exp_f32 + pk2bf_hu (compiler-visible consumers
// only — NEVER feed v_exp_f32 into opaque inline asm, r7-r10 forensics),
// builtin permlane32_swap, ones-B MFMA row sums.

__global__ __launch_bounds__(512, 4) void attn_kernel(
    const short* __restrict__ qw, const short* __restrict__ kw,
    const short* __restrict__ vtw, short* __restrict__ ow)
{
  __shared__ __align__(16) short Ks[4][4096];   // [64][64] swizzled
  __shared__ __align__(16) short Vs[4][4096];   // [64 d][64 Lw] swizzled

  const int id = blockIdx.x;
  const int xcd = id & 7, j2 = id >> 3;
  const int nh = xcd * 8 + (j2 & 7);         // 8 heads per XCD, head-coherent
  const int qt = j2 >> 3;                    // q-tile 0..7 (256 rows each)
  const int tid = threadIdx.x;
  const int lane = tid & 63, w = tid >> 6;
  const int l31 = lane & 31, hi = lane >> 5, w7 = lane & 7;

  const size_t hoff = (size_t)nh * 2048 * 64;
  const short* kh = kw + hoff;
  const short* vh = vtw + hoff;

  const int srow = tid >> 3, schunk = tid & 7;
  const int scw = (schunk ^ (srow & 7)) * 8;
  const short* ksrc = kh + srow * 64 + scw;              // + t*4096
  const short* vsrc = vh + srow * 64 + scw;              // + t*4096 (re-tiled)

  unsigned aoffh[2][4];
  #pragma unroll
  for (int T = 0; T < 2; ++T)
    #pragma unroll
    for (int s = 0; s < 4; ++s)
      aoffh[T][s] = (unsigned)((l31 + 32 * T) * 64 + (((2 * s + hi) ^ w7) * 8));

  const int qrow0 = qt * 256 + w * 32;
  short8 qfr[4];
  #pragma unroll
  for (int s = 0; s < 4; ++s)
    qfr[s] = *(const short8*)(qw + hoff + (size_t)(qrow0 + l31) * 64 + s * 16 + hi * 8);

  f32x16 oa0 = {}, oa1 = {}, lacc = {};
  short8 onesB;
  #pragma unroll
  for (int i = 0; i < 8; ++i) onesB[i] = (short)0x3F80;  // bf16 1.0

  auto compute = [&](const short* Kb, const short* Vb){
    f32x16 ss0, ss1;
    __builtin_amdgcn_s_setprio(1);
    {
      const f32x16 zz = {};
      ss0 = MFMA32(*(const short8*)&Kb[aoffh[0][0]], qfr[0], zz);
      ss1 = MFMA32(*(const short8*)&Kb[aoffh[1][0]], qfr[0], zz);
    }
    #pragma unroll
    for (int s = 1; s < 4; ++s){
      ss0 = MFMA32(*(const short8*)&Kb[aoffh[0][s]], qfr[s], ss0);
      ss1 = MFMA32(*(const short8*)&Kb[aoffh[1][s]], qfr[s], ss1);
    }
    __builtin_amdgcn_s_setprio(0);

    unsigned u0[8], u1[8];
    #pragma unroll
    for (int m = 0; m < 8; ++m){
      u0[m] = pk2bf_hu(__builtin_amdgcn_exp2f(ss0[2 * m]),
                       __builtin_amdgcn_exp2f(ss0[2 * m + 1]));
      u1[m] = pk2bf_hu(__builtin_amdgcn_exp2f(ss1[2 * m]),
                       __builtin_amdgcn_exp2f(ss1[2 * m + 1]));
    }

    short8 pa[4];
    #pragma unroll
    for (int s = 0; s < 4; ++s){
      const int sg = (s & 1) * 4;
      unsigned a0 = (s < 2) ? u0[sg + 0] : u1[sg + 0];
      unsigned a1 = (s < 2) ? u0[sg + 1] : u1[sg + 1];
      unsigned a2 = (s < 2) ? u0[sg + 2] : u1[sg + 2];
      unsigned a3 = (s < 2) ? u0[sg + 3] : u1[sg + 3];
      auto r02 = __builtin_amdgcn_permlane32_swap(a0, a2, false, false);
      auto r13 = __builtin_amdgcn_permlane32_swap(a1, a3, false, false);
      union { unsigned q[4]; short8 s8; } cv;
      cv.q[0] = (unsigned)r02[0]; cv.q[1] = (unsigned)r13[0];
      cv.q[2] = (unsigned)r02[1]; cv.q[3] = (unsigned)r13[1];
      pa[s] = cv.s8;
    }

    __builtin_amdgcn_s_setprio(1);
    #pragma unroll
    for (int s = 0; s < 4; ++s){
      oa0  = MFMA32(pa[s], *(const short8*)&Vb[aoffh[0][s]], oa0);
      oa1  = MFMA32(pa[s], *(const short8*)&Vb[aoffh[1][s]], oa1);
      lacc = MFMA32(pa[s], onesB, lacc);
    }
    __builtin_amdgcn_s_setprio(0);
  };

  // prologue: stage tiles 0,1 into buffers 0,1
  gload16(ksrc,        &Ks[0][tid * 8]);
  gload16(vsrc,        &Vs[0][tid * 8]);
  gload16(ksrc + 4096, &Ks[1][tid * 8]);
  gload16(vsrc + 4096, &Vs[1][tid * 8]);

  for (int p = 0; p < 8; ++p){
    const int t0 = p * 4;
    asm volatile("s_waitcnt vmcnt(0)" ::: "memory");
    asm volatile("s_barrier" ::: "memory");
    gload16(ksrc + (t0 + 2) * 4096, &Ks[2][tid * 8]);
    gload16(vsrc + (t0 + 2) * 4096, &Vs[2][tid * 8]);
    gload16(ksrc + (t0 + 3) * 4096, &Ks[3][tid * 8]);
    gload16(vsrc + (t0 + 3) * 4096, &Vs[3][tid * 8]);
    compute(&Ks[0][0], &Vs[0][0]);
    compute(&Ks[1][0], &Vs[1][0]);
    asm volatile("s_waitcnt vmcnt(0)" ::: "memory");
    asm volatile("s_barrier" ::: "memory");
    {
      const int ts0 = (t0 + 4) & 31;   // p=7: dummy re-stage of tiles 0,1
      const int ts1 = (t0 + 5) & 31;
      gload16(ksrc + ts0 * 4096, &Ks[0][tid * 8]);
      gload16(vsrc + ts0 * 4096, &Vs[0][tid * 8]);
      gload16(ksrc + ts1 * 4096, &Ks[1][tid * 8]);
      gload16(vsrc + ts1 * 4096, &Vs[1][tid * 8]);
    }
    compute(&Ks[2][0], &Vs[2][0]);
    compute(&Ks[3][0], &Vs[3][0]);
  }

  const int n = nh >> 4, h = nh & 15;
  #pragma unroll
  for (int j = 0; j < 16; ++j){
    const float inv = 1.0f / lacc[j];
    const int qr = (j & 3) + 8 * (j >> 2) + 4 * hi;
    const size_t base = ((size_t)n * 2048 + qrow0 + qr) * 1024 + h * 64 + l31;
    ow[base]      = f2bf(oa0[j] * inv);
    ow[base + 32] = f2bf(oa1[j] * inv);
  }
}

// ---------------- launch ----------------

extern "C" void kernel_launch(void* const* d_in, const int* in_sizes, int n_in,
                              void* d_out, int out_size, void* d_ws, size_t ws_size,
                              hipStream_t stream){
  const float* attn_in = (const float*)d_in[0];
  const float* W_qkv   = (const float*)d_in[1];
  const float* b_qkv   = (const float*)d_in[2];
  const float* W_out   = (const float*)d_in[3];
  const float* b_out   = (const float*)d_in[4];
  float* out = (float*)d_out;

  char* ws = (char*)d_ws;
  short* xb    = (short*)(ws);              // 16 MB  [8192][1024]
  short* wqT   = (short*)(ws + 16777216);   // 6 MB   [3072][1024]
  short* woT   = (short*)(ws + 23068672);   // 2 MB   [1024][1024]
  short* q_ws  = (short*)(ws + 25165824);   // 16 MB  [64][2048][64]
  short* k_ws  = (short*)(ws + 41943040);   // 16 MB
  short* vt_ws = (short*)(ws + 58720256);   // 16 MB  [64][32][64][64]
  short* o_ws  = (short*)(ws + 75497472);   // 16 MB  [8192][1024]

  cvt_x_kernel<<<4096, 256, 0, stream>>>(attn_in, xb);
  cvt_t_kernel<<<dim3(96, 32), dim3(32, 8), 0, stream>>>(W_qkv, wqT, 1024, 3072);
  cvt_t_kernel<<<dim3(32, 32), dim3(32, 8), 0, stream>>>(W_out, woT, 1024, 1024);
  gemm_bt<0><<<dim3(24, 64), 256, 0, stream>>>(xb, wqT, b_qkv, nullptr, q_ws, k_ws, vt_ws);
  attn_kernel<<<512, 512, 0, stream>>>(q_ws, k_ws, vt_ws, o_ws);
  gemm_bt<1><<<dim3(8, 64), 256, 0, stream>>>(o_ws, woT, b_out, out, nullptr, nullptr, nullptr);
}

// Round 25
// 169.274 us; speedup vs baseline: 1.9392x; 1.1066x over previous
//
#include <hip/hip_runtime.h>

typedef __attribute__((ext_vector_type(8))) short short8;
typedef __attribute__((ext_vector_type(4))) float f32x4;
typedef __attribute__((ext_vector_type(16))) float f32x16;

#define MFMA16(A,B,C) __builtin_amdgcn_mfma_f32_16x16x32_bf16(A,B,C,0,0,0)
#define MFMA32(A,B,C) __builtin_amdgcn_mfma_f32_32x32x16_bf16(A,B,C,0,0,0)

__device__ __forceinline__ short f2bf(float f){
  union { float f; unsigned int u; } v; v.f = f;
  unsigned int u = v.u;
  unsigned int r = (u + 0x7fffu + ((u >> 16) & 1u)) >> 16;
  return (short)r;
}

// Round-half-up two floats to bf16 and pack (low = x, high = y):
// 2 x v_add_u32 + 1 x v_perm_b32, all compiler-generated.
__device__ __forceinline__ unsigned pk2bf_hu(float x, float y){
  unsigned a = __builtin_bit_cast(unsigned, x) + 0x8000u;
  unsigned b = __builtin_bit_cast(unsigned, y) + 0x8000u;
  return __builtin_amdgcn_perm(b, a, 0x07060302u);  // {b.hi16, a.hi16}
}

typedef const __attribute__((address_space(1))) void* gptr_t;
typedef __attribute__((address_space(3))) void* lptr_t;

__device__ __forceinline__ void gload16(const short* g, short* l){
  __builtin_amdgcn_global_load_lds((gptr_t)g, (lptr_t)l, 16, 0, 0);
}

// ---------------- converts ----------------

__global__ __launch_bounds__(256) void cvt_x_kernel(const float* __restrict__ x,
                                                    short* __restrict__ xb){
  const size_t i = (size_t)blockIdx.x * 256 + threadIdx.x;
  const float4* p = (const float4*)x + i * 2;
  float4 a = p[0], b = p[1];
  short8 o;
  o[0]=f2bf(a.x); o[1]=f2bf(a.y); o[2]=f2bf(a.z); o[3]=f2bf(a.w);
  o[4]=f2bf(b.x); o[5]=f2bf(b.y); o[6]=f2bf(b.z); o[7]=f2bf(b.w);
  *(short8*)(xb + i * 8) = o;
}

// src[R][C] f32 -> dst[C][R] bf16
__global__ __launch_bounds__(256) void cvt_t_kernel(const float* __restrict__ src,
                                                    short* __restrict__ dst,
                                                    int R, int C){
  __shared__ float tile[32][33];
  const int tx = threadIdx.x, ty = threadIdx.y;
  const int c0 = blockIdx.x * 32, r0 = blockIdx.y * 32;
  #pragma unroll
  for (int i = 0; i < 32; i += 8)
    tile[ty + i][tx] = src[(size_t)(r0 + ty + i) * C + c0 + tx];
  __syncthreads();
  #pragma unroll
  for (int i = 0; i < 32; i += 8)
    dst[(size_t)(c0 + ty + i) * R + r0 + tx] = f2bf(tile[tx][ty + i]);
}

// ---------------- GEMM: C[M][N] = A[M][1024] * BT[N][1024]^T + bias ----------------
// r21 shell (bn fast, __launch_bounds__(256,4)) with BK=64: 16 iters of
// {stage 32KB, vmcnt(0)+syncthreads, 32 MFMA} — half the drains/barriers of
// BK=32. Row stride 128B -> attn-verified XOR swizzle (source chunk
// (tid&7)^(row&7) into LINEAR LDS, same XOR on read; row&7 == r&7 on reads).
// r24 bug fixed: stage loop is j<4 (256 thr x 16B = 32 rows/call; 4 calls
// cover the 128-row tile; j<8 overran LDS and read OOB global rows -> NaN).
// EPI 0: QKV epilogue (Q pre-scaled by 0.125*log2e). V^T stored RE-TILED:
// [head][32 Ltile][64 d][64 Lw].

template<int EPI>
__global__ __launch_bounds__(256, 4) void gemm_bt(
    const short* __restrict__ A, const short* __restrict__ BT,
    const float* __restrict__ bias,
    float* __restrict__ Cf,
    short* __restrict__ q_ws, short* __restrict__ k_ws, short* __restrict__ vt_ws)
{
  __shared__ __align__(16) short As[8192];  // [128][64], XOR-swizzled
  __shared__ __align__(16) short Bs[8192];  // [128][64], XOR-swizzled
  const int tid = threadIdx.x;
  const int bn = blockIdx.x, bm = blockIdx.y;   // bn fast (axis swap)
  const int lane = tid & 63, wid = tid >> 6;
  const int wr = wid >> 1, wc = wid & 1;
  const int r = lane & 15, g = lane >> 4;

  f32x4 acc[4][4] = {};

  // staging geometry: call j covers LDS rows j*32 + (tid>>3), linear chunk
  // tid&7; source chunk pre-swizzled by ^(row&7) so reads can unswizzle.
  const int srow_lo = tid >> 3;                       // 0..31
  const int sc8 = ((tid & 7) ^ (srow_lo & 7)) * 8;    // pre-swizzled src chunk
  const short* agb = A  + (size_t)(bm * 128 + srow_lo) * 1024 + sc8;
  const short* bgb = BT + (size_t)(bn * 128 + srow_lo) * 1024 + sc8;

  auto stage = [&](int kk){
    #pragma unroll
    for (int j = 0; j < 4; ++j){
      gload16(agb + (size_t)j * 32 * 1024 + kk * 64, &As[j * 2048 + tid * 8]);
      gload16(bgb + (size_t)j * 32 * 1024 + kk * 64, &Bs[j * 2048 + tid * 8]);
    }
  };

  for (int kk = 0; kk < 16; ++kk){
    stage(kk);
    asm volatile("s_waitcnt vmcnt(0)" ::: "memory");
    __syncthreads();
    #pragma unroll
    for (int ks = 0; ks < 2; ++ks){
      short8 a[4], b[4];
      #pragma unroll
      for (int mf = 0; mf < 4; ++mf){
        const int row = wr * 64 + mf * 16 + r;
        a[mf] = *(const short8*)&As[row * 64 + (((ks * 4 + g) ^ (r & 7)) * 8)];
      }
      #pragma unroll
      for (int nf = 0; nf < 4; ++nf){
        const int row = wc * 64 + nf * 16 + r;
        b[nf] = *(const short8*)&Bs[row * 64 + (((ks * 4 + g) ^ (r & 7)) * 8)];
      }
      #pragma unroll
      for (int mf = 0; mf < 4; ++mf)
        #pragma unroll
        for (int nf = 0; nf < 4; ++nf)
          acc[mf][nf] = MFMA16(a[mf], b[nf], acc[mf][nf]);
    }
    __syncthreads();
  }

  if (EPI == 0){
    #pragma unroll
    for (int nf = 0; nf < 4; ++nf){
      const int c = bn * 128 + wc * 64 + nf * 16 + r;
      const float bv = bias[c];
      const int type = c >> 10;
      const int h = (c & 1023) >> 6, d = c & 63;
      const float mul = (type == 0) ? 0.18033688011112042f : 1.0f;  // sc*log2e
      #pragma unroll
      for (int mf = 0; mf < 4; ++mf){
        const int row0 = bm * 128 + wr * 64 + mf * 16 + g * 4;
        const int nb = row0 >> 11, l0 = row0 & 2047;
        f32x4 v = acc[mf][nf];
        if (type == 2){
          short4 pk;
          pk.x = f2bf(v[0] + bv); pk.y = f2bf(v[1] + bv);
          pk.z = f2bf(v[2] + bv); pk.w = f2bf(v[3] + bv);
          const int head = nb * 16 + h;
          *(short4*)&vt_ws[(((size_t)head * 32 + (l0 >> 6)) * 64 + d) * 64 + (l0 & 63)] = pk;
        } else {
          short* dst = (type == 0) ? q_ws : k_ws;
          const size_t base = ((size_t)(nb * 16 + h) * 2048 + l0) * 64 + d;
          #pragma unroll
          for (int j = 0; j < 4; ++j)
            dst[base + (size_t)j * 64] = f2bf((v[j] + bv) * mul);
        }
      }
    }
  } else {
    #pragma unroll
    for (int nf = 0; nf < 4; ++nf){
      const int c = bn * 128 + wc * 64 + nf * 16 + r;
      const float bv = bias[c];
      #pragma unroll
      for (int mf = 0; mf < 4; ++mf){
        const int row0 = bm * 128 + wr * 64 + mf * 16 + g * 4;
        f32x4 v = acc[mf][nf];
        #pragma unroll
        for (int j = 0; j < 4; ++j)
          Cf[(size_t)(row0 + j) * 1024 + c] = v[j] + bv;
      }
    }
  }
}

// ---------------- flash attention: 2-tiles-per-barrier LDS pipeline ---------
// Frozen at r23 (verified best, 80.5us): shell = sync round of 2 tiles,
// vmcnt(0) + fenced s_barrier per round, 4 buffers with literal indices;
// s_setprio(1) around MFMA clusters. Core = swapped QK^T at 32x32x16,
// raw v_exp_f32 packed by pk2bf_hu (compiler-visible consumers only —
// NEVER feed v_exp_f32 into opaque inline asm, r7-r10 forensics),
// builtin permlane32_swap, ones-B MFMA row sums.

__global__ __launch_bounds__(512, 4) void attn_kernel(
    const short* __restrict__ qw, const short* __restrict__ kw,
    const short* __restrict__ vtw, short* __restrict__ ow)
{
  __shared__ __align__(16) short Ks[4][4096];   // [64][64] swizzled
  __shared__ __align__(16) short Vs[4][4096];   // [64 d][64 Lw] swizzled

  const int id = blockIdx.x;
  const int xcd = id & 7, j2 = id >> 3;
  const int nh = xcd * 8 + (j2 & 7);         // 8 heads per XCD, head-coherent
  const int qt = j2 >> 3;                    // q-tile 0..7 (256 rows each)
  const int tid = threadIdx.x;
  const int lane = tid & 63, w = tid >> 6;
  const int l31 = lane & 31, hi = lane >> 5, w7 = lane & 7;

  const size_t hoff = (size_t)nh * 2048 * 64;
  const short* kh = kw + hoff;
  const short* vh = vtw + hoff;

  const int srow = tid >> 3, schunk = tid & 7;
  const int scw = (schunk ^ (srow & 7)) * 8;
  const short* ksrc = kh + srow * 64 + scw;              // + t*4096
  const short* vsrc = vh + srow * 64 + scw;              // + t*4096 (re-tiled)

  unsigned aoffh[2][4];
  #pragma unroll
  for (int T = 0; T < 2; ++T)
    #pragma unroll
    for (int s = 0; s < 4; ++s)
      aoffh[T][s] = (unsigned)((l31 + 32 * T) * 64 + (((2 * s + hi) ^ w7) * 8));

  const int qrow0 = qt * 256 + w * 32;
  short8 qfr[4];
  #pragma unroll
  for (int s = 0; s < 4; ++s)
    qfr[s] = *(const short8*)(qw + hoff + (size_t)(qrow0 + l31) * 64 + s * 16 + hi * 8);

  f32x16 oa0 = {}, oa1 = {}, lacc = {};
  short8 onesB;
  #pragma unroll
  for (int i = 0; i < 8; ++i) onesB[i] = (short)0x3F80;  // bf16 1.0

  auto compute = [&](const short* Kb, const short* Vb){
    f32x16 ss0, ss1;
    __builtin_amdgcn_s_setprio(1);
    {
      const f32x16 zz = {};
      ss0 = MFMA32(*(const short8*)&Kb[aoffh[0][0]], qfr[0], zz);
      ss1 = MFMA32(*(const short8*)&Kb[aoffh[1][0]], qfr[0], zz);
    }
    #pragma unroll
    for (int s = 1; s < 4; ++s){
      ss0 = MFMA32(*(const short8*)&Kb[aoffh[0][s]], qfr[s], ss0);
      ss1 = MFMA32(*(const short8*)&Kb[aoffh[1][s]], qfr[s], ss1);
    }
    __builtin_amdgcn_s_setprio(0);

    unsigned u0[8], u1[8];
    #pragma unroll
    for (int m = 0; m < 8; ++m){
      u0[m] = pk2bf_hu(__builtin_amdgcn_exp2f(ss0[2 * m]),
                       __builtin_amdgcn_exp2f(ss0[2 * m + 1]));
      u1[m] = pk2bf_hu(__builtin_amdgcn_exp2f(ss1[2 * m]),
                       __builtin_amdgcn_exp2f(ss1[2 * m + 1]));
    }

    short8 pa[4];
    #pragma unroll
    for (int s = 0; s < 4; ++s){
      const int sg = (s & 1) * 4;
      unsigned a0 = (s < 2) ? u0[sg + 0] : u1[sg + 0];
      unsigned a1 = (s < 2) ? u0[sg + 1] : u1[sg + 1];
      unsigned a2 = (s < 2) ? u0[sg + 2] : u1[sg + 2];
      unsigned a3 = (s < 2) ? u0[sg + 3] : u1[sg + 3];
      auto r02 = __builtin_amdgcn_permlane32_swap(a0, a2, false, false);
      auto r13 = __builtin_amdgcn_permlane32_swap(a1, a3, false, false);
      union { unsigned q[4]; short8 s8; } cv;
      cv.q[0] = (unsigned)r02[0]; cv.q[1] = (unsigned)r13[0];
      cv.q[2] = (unsigned)r02[1]; cv.q[3] = (unsigned)r13[1];
      pa[s] = cv.s8;
    }

    __builtin_amdgcn_s_setprio(1);
    #pragma unroll
    for (int s = 0; s < 4; ++s){
      oa0  = MFMA32(pa[s], *(const short8*)&Vb[aoffh[0][s]], oa0);
      oa1  = MFMA32(pa[s], *(const short8*)&Vb[aoffh[1][s]], oa1);
      lacc = MFMA32(pa[s], onesB, lacc);
    }
    __builtin_amdgcn_s_setprio(0);
  };

  // prologue: stage tiles 0,1 into buffers 0,1
  gload16(ksrc,        &Ks[0][tid * 8]);
  gload16(vsrc,        &Vs[0][tid * 8]);
  gload16(ksrc + 4096, &Ks[1][tid * 8]);
  gload16(vsrc + 4096, &Vs[1][tid * 8]);

  for (int p = 0; p < 8; ++p){
    const int t0 = p * 4;
    asm volatile("s_waitcnt vmcnt(0)" ::: "memory");
    asm volatile("s_barrier" ::: "memory");
    gload16(ksrc + (t0 + 2) * 4096, &Ks[2][tid * 8]);
    gload16(vsrc + (t0 + 2) * 4096, &Vs[2][tid * 8]);
    gload16(ksrc + (t0 + 3) * 4096, &Ks[3][tid * 8]);
    gload16(vsrc + (t0 + 3) * 4096, &Vs[3][tid * 8]);
    compute(&Ks[0][0], &Vs[0][0]);
    compute(&Ks[1][0], &Vs[1][0]);
    asm volatile("s_waitcnt vmcnt(0)" ::: "memory");
    asm volatile("s_barrier" ::: "memory");
    {
      const int ts0 = (t0 + 4) & 31;   // p=7: dummy re-stage of tiles 0,1
      const int ts1 = (t0 + 5) & 31;
      gload16(ksrc + ts0 * 4096, &Ks[0][tid * 8]);
      gload16(vsrc + ts0 * 4096, &Vs[0][tid * 8]);
      gload16(ksrc + ts1 * 4096, &Ks[1][tid * 8]);
      gload16(vsrc + ts1 * 4096, &Vs[1][tid * 8]);
    }
    compute(&Ks[2][0], &Vs[2][0]);
    compute(&Ks[3][0], &Vs[3][0]);
  }

  const int n = nh >> 4, h = nh & 15;
  #pragma unroll
  for (int j = 0; j < 16; ++j){
    const float inv = 1.0f / lacc[j];
    const int qr = (j & 3) + 8 * (j >> 2) + 4 * hi;
    const size_t base = ((size_t)n * 2048 + qrow0 + qr) * 1024 + h * 64 + l31;
    ow[base]      = f2bf(oa0[j] * inv);
    ow[base + 32] = f2bf(oa1[j] * inv);
  }
}

// ---------------- launch ----------------

extern "C" void kernel_launch(void* const* d_in, const int* in_sizes, int n_in,
                              void* d_out, int out_size, void* d_ws, size_t ws_size,
                              hipStream_t stream){
  const float* attn_in = (const float*)d_in[0];
  const float* W_qkv   = (const float*)d_in[1];
  const float* b_qkv   = (const float*)d_in[2];
  const float* W_out   = (const float*)d_in[3];
  const float* b_out   = (const float*)d_in[4];
  float* out = (float*)d_out;

  char* ws = (char*)d_ws;
  short* xb    = (short*)(ws);              // 16 MB  [8192][1024]
  short* wqT   = (short*)(ws + 16777216);   // 6 MB   [3072][1024]
  short* woT   = (short*)(ws + 23068672);   // 2 MB   [1024][1024]
  short* q_ws  = (short*)(ws + 25165824);   // 16 MB  [64][2048][64]
  short* k_ws  = (short*)(ws + 41943040);   // 16 MB
  short* vt_ws = (short*)(ws + 58720256);   // 16 MB  [64][32][64][64]
  short* o_ws  = (short*)(ws + 75497472);   // 16 MB  [8192][1024]

  cvt_x_kernel<<<4096, 256, 0, stream>>>(attn_in, xb);
  cvt_t_kernel<<<dim3(96, 32), dim3(32, 8), 0, stream>>>(W_qkv, wqT, 1024, 3072);
  cvt_t_kernel<<<dim3(32, 32), dim3(32, 8), 0, stream>>>(W_out, woT, 1024, 1024);
  gemm_bt<0><<<dim3(24, 64), 256, 0, stream>>>(xb, wqT, b_qkv, nullptr, q_ws, k_ws, vt_ws);
  attn_kernel<<<512, 512, 0, stream>>>(q_ws, k_ws, vt_ws, o_ws);
  gemm_bt<1><<<dim3(8, 64), 256, 0, stream>>>(o_ws, woT, b_out, out, nullptr, nullptr, nullptr);
}